// Round 5
// baseline (199.350 us; speedup 1.0000x reference)
//
#include <hip/hip_runtime.h>
#include <stdint.h>

// Problem constants: B=16, T=1024, N=512
#define BB 16
#define TT 1024
#define NN 512

typedef unsigned short u16;
typedef __bf16 bf16_t;
typedef bf16_t bf16x8 __attribute__((ext_vector_type(8)));
typedef float f32x4 __attribute__((ext_vector_type(4)));

struct alignas(8) U16x4 { u16 x, y, z, w; };
struct alignas(16) F32x4 { float x, y, z, w; };

__device__ __forceinline__ u16 f2bf(float f) {
    union { float f; uint32_t u; } v; v.f = f;
    uint32_t r = v.u + 0x7fffu + ((v.u >> 16) & 1u);
    return (u16)(r >> 16);
}

__device__ __forceinline__ void gload_lds16(const void* g, void* l) {
    __builtin_amdgcn_global_load_lds(
        (const __attribute__((address_space(1))) void*)g,
        (__attribute__((address_space(3))) void*)l, 16, 0, 0);
}

// Bijective XCD-aware swizzle (m204)
__device__ __forceinline__ void xcd_swizzle(int gx, int gy, int& bx, int& by) {
    const int nwg  = gx * gy;
    const int orig = by * gx + bx;
    const int q = nwg >> 3, r = nwg & 7;
    const int xcd = orig & 7, loc = orig >> 3;
    const int swz = (xcd < r ? xcd * (q + 1) : r * (q + 1) + (xcd - r) * q) + loc;
    bx = swz % gx;
    by = swz / gx;
}

// ---------------------------------------------------------------------------
// cvt_x: x fp32 [B,T,N] -> xb bf16 [B,T,N] AND xT bf16 [B,N,T]
// 64x64 LDS tile transpose; grid (T/64, N/64, B) = (16,8,16).
// ---------------------------------------------------------------------------
__global__ __launch_bounds__(256)
void cvt_x(const float* __restrict__ x, u16* __restrict__ xb, u16* __restrict__ xT)
{
    __shared__ u16 tile[64][70];   // +6 pad -> phase-2 bank spread
    const int b  = blockIdx.z;
    const int t0 = blockIdx.x * 64;
    const int n0 = blockIdx.y * 64;
    const int i  = threadIdx.x;
#pragma unroll
    for (int rep = 0; rep < 4; rep++) {
        const int lin = rep * 256 + i;
        const int r = lin >> 4, c4 = (lin & 15) * 4;
        const long src = ((long)(b * TT + t0 + r)) * NN + n0 + c4;
        F32x4 f = *(const F32x4*)&x[src];
        U16x4 u;
        u.x = f2bf(f.x); u.y = f2bf(f.y); u.z = f2bf(f.z); u.w = f2bf(f.w);
        *(U16x4*)&xb[src] = u;
        tile[r][c4] = u.x; tile[r][c4 + 1] = u.y; tile[r][c4 + 2] = u.z; tile[r][c4 + 3] = u.w;
    }
    __syncthreads();
#pragma unroll
    for (int rep = 0; rep < 4; rep++) {
        const int lin = rep * 256 + i;
        const int n = lin >> 4, t4 = (lin & 15) * 4;
        U16x4 u;
        u.x = tile[t4][n]; u.y = tile[t4 + 1][n]; u.z = tile[t4 + 2][n]; u.w = tile[t4 + 3][n];
        *(U16x4*)&xT[((long)(b * NN + n0 + n)) * TT + t0 + t4] = u;
    }
}

// ---------------------------------------------------------------------------
// cvt_w: weights -> wb = [Wq | Wk | WvT | Wp] bf16, each 512x512.
// z=0,1,3: natural convert; z=2: Wv transposed (WvT[i,m] = Wv[m,i]).
// grid (8,8,4), 64x64 tiles.
// ---------------------------------------------------------------------------
__global__ __launch_bounds__(256)
void cvt_w(const float* __restrict__ Wq, const float* __restrict__ Wk,
           const float* __restrict__ Wv, const float* __restrict__ Wp,
           u16* __restrict__ wb)
{
    __shared__ u16 tile[64][70];
    const int z  = blockIdx.z;
    const int r0 = blockIdx.x * 64;
    const int c0 = blockIdx.y * 64;
    const int i  = threadIdx.x;
    const float* src = (z == 0) ? Wq : (z == 1) ? Wk : (z == 2) ? Wv : Wp;
    u16* dst = wb + z * 262144;
    if (z != 2) {
#pragma unroll
        for (int rep = 0; rep < 4; rep++) {
            const int lin = rep * 256 + i;
            const int r = lin >> 4, c4 = (lin & 15) * 4;
            F32x4 f = *(const F32x4*)&src[(r0 + r) * 512 + c0 + c4];
            U16x4 u;
            u.x = f2bf(f.x); u.y = f2bf(f.y); u.z = f2bf(f.z); u.w = f2bf(f.w);
            *(U16x4*)&dst[(r0 + r) * 512 + c0 + c4] = u;
        }
    } else {
#pragma unroll
        for (int rep = 0; rep < 4; rep++) {
            const int lin = rep * 256 + i;
            const int r = lin >> 4, c4 = (lin & 15) * 4;
            F32x4 f = *(const F32x4*)&src[(r0 + r) * 512 + c0 + c4];
            tile[r][c4]     = f2bf(f.x); tile[r][c4 + 1] = f2bf(f.y);
            tile[r][c4 + 2] = f2bf(f.z); tile[r][c4 + 3] = f2bf(f.w);
        }
        __syncthreads();
#pragma unroll
        for (int rep = 0; rep < 4; rep++) {
            const int lin = rep * 256 + i;
            const int n = lin >> 4, t4 = (lin & 15) * 4;
            U16x4 u;
            u.x = tile[t4][n]; u.y = tile[t4 + 1][n]; u.z = tile[t4 + 2][n]; u.w = tile[t4 + 3][n];
            *(U16x4*)&dst[(c0 + n) * 512 + r0 + t4] = u;
        }
    }
}

// ---------------------------------------------------------------------------
// NT GEMM: C[i,j] = sum_k A[i,k] * Bt[j,k]   (A: [M,K] ld=lda, Bt: [Nc,K] ld=ldb)
// bf16 in (raw u16), fp32 accum. 128x128 tile, BK=32, 4 waves, 4x4 frags of
// mfma_f32_16x16x32_bf16. Double-buffered counted-vmcnt pipeline (T3/T4 min
// recipe): stage kt+1, s_waitcnt vmcnt(4) (never 0 steady-state), raw
// s_barrier, 16 MFMA, barrier. LDS 64B rows, swizzle byte^=((row>>1)&3)<<4
// applied both-sides (pre-swizzled global source + swizzled ds_read).
// MODE 0: bf16 natural store (+z*sC);  MODE 2: fp32;  MODE 3: fp32 + bias[j].
// ---------------------------------------------------------------------------
template<int MODE>
__global__ __launch_bounds__(256)
void gemm_nt(const u16* __restrict__ Ag, const u16* __restrict__ Bg,
             void* __restrict__ Cg, const float* __restrict__ bias,
             int Nc, int K, int lda, int ldb,
             long sA, long sB, long sC)
{
    const u16* A  = Ag + (long)blockIdx.z * sA;
    const u16* Bt = Bg + (long)blockIdx.z * sB;

    __shared__ u16 As[2][4096];   // 2 x (128 rows x 32 cols bf16) = 2 x 8 KB
    __shared__ u16 Bs[2][4096];

    int bx = blockIdx.x, by = blockIdx.y;
    xcd_swizzle(gridDim.x, gridDim.y, bx, by);

    const int tid  = threadIdx.x;
    const int wave = tid >> 6;
    const int lane = tid & 63;
    const int arow0 = by * 128;
    const int brow0 = bx * 128;
    const int wr = (wave >> 1) * 64;
    const int wc = (wave & 1) * 64;

    // staging: rows tid>>2 and +64; 16B at (tid&3)*16, source pre-swizzled
    const int srow = tid >> 2;
    const int sf   = ((srow >> 1) & 3) << 4;
    const int gcol = ((tid & 3) << 4) ^ sf;
    const char* Asrc = (const char*)A  + (long)(arow0 + srow) * lda * 2 + gcol;
    const char* Bsrc = (const char*)Bt + (long)(brow0 + srow) * ldb * 2 + gcol;
    const long rstepA = (long)64 * lda * 2;
    const long rstepB = (long)64 * ldb * 2;

    f32x4 zero = {0.f, 0.f, 0.f, 0.f};
    f32x4 acc[4][4];
#pragma unroll
    for (int i = 0; i < 4; i++)
#pragma unroll
        for (int j = 0; j < 4; j++) acc[i][j] = zero;

    const int kTiles = K >> 5;

    auto stage = [&](int buf, int kt) {
        const long kb = (long)kt * 64;
        char* ad = (char*)As + buf * 8192 + tid * 16;
        char* bd = (char*)Bs + buf * 8192 + tid * 16;
        gload_lds16(Asrc + kb,          ad);
        gload_lds16(Bsrc + kb,          bd);
        gload_lds16(Asrc + rstepA + kb, ad + 4096);
        gload_lds16(Bsrc + rstepB + kb, bd + 4096);
    };

    stage(0, 0);
    int cur = 0;
    const int kbyte = (lane >> 4) << 4;
    const int rA = lane & 15;

    for (int kt = 0; kt < kTiles; ++kt) {
        if (kt + 1 < kTiles) {
            stage(cur ^ 1, kt + 1);
            asm volatile("s_waitcnt vmcnt(4)" ::: "memory");
        } else {
            asm volatile("s_waitcnt vmcnt(0)" ::: "memory");
        }
        __builtin_amdgcn_s_barrier();
        asm volatile("" ::: "memory");

        bf16x8 av[4], bv[4];
        const char* as = (const char*)As + cur * 8192;
        const char* bs = (const char*)Bs + cur * 8192;
#pragma unroll
        for (int m = 0; m < 4; m++) {
            const int row = wr + m * 16 + rA;
            av[m] = *(const bf16x8*)(as + row * 64 + (kbyte ^ (((row >> 1) & 3) << 4)));
        }
#pragma unroll
        for (int n = 0; n < 4; n++) {
            const int row = wc + n * 16 + rA;
            bv[n] = *(const bf16x8*)(bs + row * 64 + (kbyte ^ (((row >> 1) & 3) << 4)));
        }
#pragma unroll
        for (int m = 0; m < 4; m++)
#pragma unroll
            for (int n = 0; n < 4; n++)
                acc[m][n] = __builtin_amdgcn_mfma_f32_16x16x32_bf16(av[m], bv[n], acc[m][n], 0, 0, 0);

        asm volatile("" ::: "memory");
        __builtin_amdgcn_s_barrier();
        cur ^= 1;
    }

    // epilogue. C/D layout: col = lane&15, row = (lane>>4)*4 + r  [m89/m91]
    const int r0 = (lane >> 4) << 2;
    const int cl = lane & 15;
#pragma unroll
    for (int m = 0; m < 4; m++) {
        const long gm = (long)arow0 + wr + m * 16 + r0;
#pragma unroll
        for (int n = 0; n < 4; n++) {
            const long gn = (long)brow0 + wc + n * 16 + cl;
            if (MODE == 0) {
                u16* O = (u16*)Cg + blockIdx.z * sC;
#pragma unroll
                for (int r = 0; r < 4; r++)
                    O[(gm + r) * Nc + gn] = f2bf(acc[m][n][r]);
            } else {
                float* O = (float*)Cg + blockIdx.z * sC;
                const float bb = (MODE == 3) ? bias[gn] : 0.f;
#pragma unroll
                for (int r = 0; r < 4; r++)
                    O[(gm + r) * Nc + gn] = acc[m][n][r] + bb;
            }
        }
    }
}

// ---------------------------------------------------------------------------
// Row softmax over 512 fp32 logits (scale 512^-0.5 folded in), bf16 P written
// IN-PLACE over the fp32 row (P row stride = 1024 u16 = fp32 row stride).
// One block (256 thr) per row; all reads precede all writes (block syncs).
// ---------------------------------------------------------------------------
__global__ __launch_bounds__(256)
void softmax_rows(float* __restrict__ S)
{
    const long r = blockIdx.x;
    float* row = S + r * 512;
    const int t = threadIdx.x;
    const int lane = t & 63, wave = t >> 6;
    const float scale = 0.04419417382415922f;  // 512^-0.5

    float a = row[t] * scale;
    float b = row[t + 256] * scale;

    float m = fmaxf(a, b);
#pragma unroll
    for (int o = 32; o; o >>= 1) m = fmaxf(m, __shfl_xor(m, o, 64));

    __shared__ float red[8];
    if (lane == 0) red[wave] = m;
    __syncthreads();
    m = fmaxf(fmaxf(red[0], red[1]), fmaxf(red[2], red[3]));

    float e0 = __expf(a - m), e1 = __expf(b - m);
    float s = e0 + e1;
#pragma unroll
    for (int o = 32; o; o >>= 1) s += __shfl_xor(s, o, 64);
    if (lane == 0) red[wave + 4] = s;
    __syncthreads();
    s = red[4] + red[5] + red[6] + red[7];
    const float inv = 1.f / s;

    u16* P = (u16*)row;
    P[t]       = f2bf(e0 * inv);
    P[t + 256] = f2bf(e1 * inv);
}

// ---------------------------------------------------------------------------
// Algebraic restructure:
//   G[b] = x[b]^T x[b]                (symmetric)       [B,512,512] bf16
//   H[b] = Wq G[b]  (NT via symmetry: Bt=G)             [B,512,512] bf16
//   S[b] = H[b] Wk^T                                    [B,512,512] fp32
//   attn = softmax(S * 512^-0.5)  in-place bf16
//   R[b] = attn[b] Wv   (NT: Bt = WvT)                  [B,512,512] bf16
//   px[b] = x[b] R[b]^T                                 [B,1024,512] bf16
//   out = px Wp^T + bp                                  fp32
// ---------------------------------------------------------------------------
extern "C" void kernel_launch(void* const* d_in, const int* in_sizes, int n_in,
                              void* d_out, int out_size, void* d_ws, size_t ws_size,
                              hipStream_t stream)
{
    (void)in_sizes; (void)n_in; (void)out_size; (void)ws_size;
    const float* x  = (const float*)d_in[0];
    const float* Wq = (const float*)d_in[1];
    const float* Wk = (const float*)d_in[2];
    const float* Wv = (const float*)d_in[3];
    const float* Wp = (const float*)d_in[4];
    const float* bp = (const float*)d_in[5];
    float* out = (float*)d_out;

    char* ws = (char*)d_ws;
    size_t o = 0;
    auto alloc = [&](size_t bytes) {
        char* p = ws + o;
        o = (o + bytes + 255) & ~(size_t)255;
        return p;
    };
    u16* xb = (u16*)alloc((size_t)BB * TT * NN * 2);    // x bf16 [B,T,N]
    u16* xT = (u16*)alloc((size_t)BB * NN * TT * 2);    // x^T bf16 [B,N,T]
    u16* wb = (u16*)alloc((size_t)4 * NN * NN * 2);     // [Wq|Wk|WvT|Wp]
    u16* G  = (u16*)alloc((size_t)BB * NN * NN * 2);
    u16* H  = (u16*)alloc((size_t)BB * NN * NN * 2);
    float* S = (float*)alloc((size_t)BB * NN * NN * 4); // logits / attn in-place
    u16* R  = (u16*)alloc((size_t)BB * NN * NN * 2);
    u16* px = (u16*)alloc((size_t)BB * TT * NN * 2);

    const u16* wqb  = wb;
    const u16* wkb  = wb + 1 * 262144;
    const u16* wvtb = wb + 2 * 262144;
    const u16* wpb  = wb + 3 * 262144;
    const long NSQ = (long)NN * NN;

    cvt_x<<<dim3(16, 8, 16), dim3(256), 0, stream>>>(x, xb, xT);
    cvt_w<<<dim3(8, 8, 4),  dim3(256), 0, stream>>>(Wq, Wk, Wv, Wp, wb);

    const dim3 blk(256);

    // G[b] = xT[b] · xT[b]^T  (K = T = 1024)
    gemm_nt<0><<<dim3(4, 4, 16), blk, 0, stream>>>(xT, xT, G, nullptr,
        NN, TT, TT, TT, (long)NN * TT, (long)NN * TT, NSQ);

    // H[b] = Wq · G[b]  (Bt = G, symmetric; sA = 0 shares Wq)
    gemm_nt<0><<<dim3(4, 4, 16), blk, 0, stream>>>(wqb, G, H, nullptr,
        NN, NN, NN, NN, 0, NSQ, NSQ);

    // S[b] = H[b] · Wk^T  (fp32 out)
    gemm_nt<2><<<dim3(4, 4, 16), blk, 0, stream>>>(H, wkb, S, nullptr,
        NN, NN, NN, NN, NSQ, 0, NSQ);

    // attn = softmax(S * scale), bf16 in-place (row stride 1024 u16)
    softmax_rows<<<dim3(BB * NN), blk, 0, stream>>>(S);

    // R[b] = attn[b] · Wv  (A = attn, lda = 1024 u16; Bt = WvT)
    gemm_nt<0><<<dim3(4, 4, 16), blk, 0, stream>>>((const u16*)S, wvtb, R, nullptr,
        NN, NN, 1024, NN, (long)NN * 1024, 0, NSQ);

    // px[b] = x[b] · R[b]^T
    gemm_nt<0><<<dim3(4, 8, 16), blk, 0, stream>>>(xb, R, px, nullptr,
        NN, NN, NN, NN, (long)TT * NN, NSQ, (long)TT * NN);

    // out = px · Wp^T + bp  (fp32)
    gemm_nt<3><<<dim3(4, 128, 1), blk, 0, stream>>>(px, wpb, out, bp,
        NN, NN, NN, NN, 0, 0, 0);
}

// Round 7
// 195.308 us; speedup vs baseline: 1.0207x; 1.0207x over previous
//
#include <hip/hip_runtime.h>
#include <stdint.h>

// Problem constants: B=16, T=1024, N=512
#define BB 16
#define TT 1024
#define NN 512

typedef unsigned short u16;
typedef __bf16 bf16_t;
typedef bf16_t bf16x8 __attribute__((ext_vector_type(8)));
typedef float f32x4 __attribute__((ext_vector_type(4)));

struct alignas(8) U16x4 { u16 x, y, z, w; };
struct alignas(16) F32x4 { float x, y, z, w; };

__device__ __forceinline__ u16 f2bf(float f) {
    union { float f; uint32_t u; } v; v.f = f;
    uint32_t r = v.u + 0x7fffu + ((v.u >> 16) & 1u);
    return (u16)(r >> 16);
}

__device__ __forceinline__ void gload_lds16(const void* g, void* l) {
    __builtin_amdgcn_global_load_lds(
        (const __attribute__((address_space(1))) void*)g,
        (__attribute__((address_space(3))) void*)l, 16, 0, 0);
}

// Bijective XCD-aware swizzle (m204)
__device__ __forceinline__ void xcd_swizzle(int gx, int gy, int& bx, int& by) {
    const int nwg  = gx * gy;
    const int orig = by * gx + bx;
    const int q = nwg >> 3, r = nwg & 7;
    const int xcd = orig & 7, loc = orig >> 3;
    const int swz = (xcd < r ? xcd * (q + 1) : r * (q + 1) + (xcd - r) * q) + loc;
    bx = swz % gx;
    by = swz / gx;
}

// ---------------------------------------------------------------------------
// cvt_fused: z<16  : x fp32 [B,T,N] -> xb bf16 [B,T,N] AND xT bf16 [B,N,T]
//            z>=16 : weights -> wb = [Wq | Wk | WvT | Wp] bf16 (WvT transposed)
// grid (16, 8, 18), 256 threads, 64x64 tiles.
// ---------------------------------------------------------------------------
__global__ __launch_bounds__(256)
void cvt_fused(const float* __restrict__ x,
               const float* __restrict__ Wq, const float* __restrict__ Wk,
               const float* __restrict__ Wv, const float* __restrict__ Wp,
               u16* __restrict__ xb, u16* __restrict__ xT, u16* __restrict__ wb)
{
    __shared__ u16 tile[64][70];
    const int i = threadIdx.x;
    if (blockIdx.z < 16) {
        const int b  = blockIdx.z;
        const int t0 = blockIdx.x * 64;
        const int n0 = blockIdx.y * 64;
#pragma unroll
        for (int rep = 0; rep < 4; rep++) {
            const int lin = rep * 256 + i;
            const int r = lin >> 4, c4 = (lin & 15) * 4;
            const long src = ((long)(b * TT + t0 + r)) * NN + n0 + c4;
            F32x4 f = *(const F32x4*)&x[src];
            U16x4 u;
            u.x = f2bf(f.x); u.y = f2bf(f.y); u.z = f2bf(f.z); u.w = f2bf(f.w);
            *(U16x4*)&xb[src] = u;
            tile[r][c4] = u.x; tile[r][c4 + 1] = u.y; tile[r][c4 + 2] = u.z; tile[r][c4 + 3] = u.w;
        }
        __syncthreads();
#pragma unroll
        for (int rep = 0; rep < 4; rep++) {
            const int lin = rep * 256 + i;
            const int n = lin >> 4, t4 = (lin & 15) * 4;
            U16x4 u;
            u.x = tile[t4][n]; u.y = tile[t4 + 1][n]; u.z = tile[t4 + 2][n]; u.w = tile[t4 + 3][n];
            *(U16x4*)&xT[((long)(b * NN + n0 + n)) * TT + t0 + t4] = u;
        }
    } else {
        // 256 weight tiles split over z=16,17
        const int idx = (blockIdx.z - 16) * 128 + blockIdx.y * 16 + blockIdx.x;
        const int w = idx >> 6, wt = idx & 63;
        const int r0 = (wt >> 3) * 64, c0 = (wt & 7) * 64;
        const float* src = (w == 0) ? Wq : (w == 1) ? Wk : (w == 2) ? Wv : Wp;
        u16* dst = wb + w * 262144;
        if (w != 2) {
#pragma unroll
            for (int rep = 0; rep < 4; rep++) {
                const int lin = rep * 256 + i;
                const int r = lin >> 4, c4 = (lin & 15) * 4;
                F32x4 f = *(const F32x4*)&src[(r0 + r) * 512 + c0 + c4];
                U16x4 u;
                u.x = f2bf(f.x); u.y = f2bf(f.y); u.z = f2bf(f.z); u.w = f2bf(f.w);
                *(U16x4*)&dst[(r0 + r) * 512 + c0 + c4] = u;
            }
        } else {   // WvT[i,m] = Wv[m,i]
#pragma unroll
            for (int rep = 0; rep < 4; rep++) {
                const int lin = rep * 256 + i;
                const int r = lin >> 4, c4 = (lin & 15) * 4;
                F32x4 f = *(const F32x4*)&src[(r0 + r) * 512 + c0 + c4];
                tile[r][c4]     = f2bf(f.x); tile[r][c4 + 1] = f2bf(f.y);
                tile[r][c4 + 2] = f2bf(f.z); tile[r][c4 + 3] = f2bf(f.w);
            }
            __syncthreads();
#pragma unroll
            for (int rep = 0; rep < 4; rep++) {
                const int lin = rep * 256 + i;
                const int n = lin >> 4, t4 = (lin & 15) * 4;
                U16x4 u;
                u.x = tile[t4][n]; u.y = tile[t4 + 1][n]; u.z = tile[t4 + 2][n]; u.w = tile[t4 + 3][n];
                *(U16x4*)&dst[(c0 + n) * 512 + r0 + t4] = u;
            }
        }
    }
}

// ---------------------------------------------------------------------------
// NT GEMM: C[i,j] = sum_k A[i,k] * Bt[j,k]   (A: [M,K] ld=lda, Bt: [Nc,K] ld=ldb)
// bf16 in (raw u16), fp32 accum. 128x128 tile, BK=32, 4 waves, 4x4 frags of
// mfma_f32_16x16x32_bf16. 2-DEEP prefetch: 3-buffer LDS ring, steady-state
// s_waitcnt vmcnt(8) (tiles kt+1, kt+2 in flight across the barrier), drain
// 8 -> 4 -> 0 at the tail. LDS 64B rows, swizzle byte ^= ((row>>1)&3)<<4
// applied both-sides (pre-swizzled global source + swizzled ds_read).
// MODE 0: bf16 natural store (+z*sC);  MODE 2: fp32;  MODE 3: fp32 + bias[j].
// ---------------------------------------------------------------------------
template<int MODE>
__global__ __launch_bounds__(256)
void gemm_nt(const u16* __restrict__ Ag, const u16* __restrict__ Bg,
             void* __restrict__ Cg, const float* __restrict__ bias,
             int Nc, int K, int lda, int ldb,
             long sA, long sB, long sC)
{
    const u16* A  = Ag + (long)blockIdx.z * sA;
    const u16* Bt = Bg + (long)blockIdx.z * sB;

    __shared__ u16 As[3][4096];   // 3 x (128 rows x 32 cols bf16) = 3 x 8 KB
    __shared__ u16 Bs[3][4096];

    int bx = blockIdx.x, by = blockIdx.y;
    xcd_swizzle(gridDim.x, gridDim.y, bx, by);

    const int tid  = threadIdx.x;
    const int wave = tid >> 6;
    const int lane = tid & 63;
    const int arow0 = by * 128;
    const int brow0 = bx * 128;
    const int wr = (wave >> 1) * 64;
    const int wc = (wave & 1) * 64;

    // staging: rows tid>>2 and +64; 16B at (tid&3)*16, source pre-swizzled
    const int srow = tid >> 2;
    const int sf   = ((srow >> 1) & 3) << 4;
    const int gcol = ((tid & 3) << 4) ^ sf;
    const char* Asrc = (const char*)A  + (long)(arow0 + srow) * lda * 2 + gcol;
    const char* Bsrc = (const char*)Bt + (long)(brow0 + srow) * ldb * 2 + gcol;
    const long rstepA = (long)64 * lda * 2;
    const long rstepB = (long)64 * ldb * 2;

    f32x4 zero = {0.f, 0.f, 0.f, 0.f};
    f32x4 acc[4][4];
#pragma unroll
    for (int i = 0; i < 4; i++)
#pragma unroll
        for (int j = 0; j < 4; j++) acc[i][j] = zero;

    const int kTiles = K >> 5;

    auto stage = [&](int buf, int kt) {
        const long kb = (long)kt * 64;
        char* ad = (char*)As + buf * 8192 + tid * 16;
        char* bd = (char*)Bs + buf * 8192 + tid * 16;
        gload_lds16(Asrc + kb,          ad);
        gload_lds16(Bsrc + kb,          bd);
        gload_lds16(Asrc + rstepA + kb, ad + 4096);
        gload_lds16(Bsrc + rstepB + kb, bd + 4096);
    };

    stage(0, 0);
    stage(1, 1);
    int cur = 0, nxt2 = 2;
    const int kbyte = (lane >> 4) << 4;
    const int rA = lane & 15;

    for (int kt = 0; kt < kTiles; ++kt) {
        if (kt + 2 < kTiles) {
            stage(nxt2, kt + 2);
            asm volatile("s_waitcnt vmcnt(8)" ::: "memory");
        } else if (kt + 1 < kTiles) {
            asm volatile("s_waitcnt vmcnt(4)" ::: "memory");
        } else {
            asm volatile("s_waitcnt vmcnt(0)" ::: "memory");
        }
        __builtin_amdgcn_s_barrier();
        asm volatile("" ::: "memory");

        bf16x8 av[4], bv[4];
        const char* as = (const char*)As + cur * 8192;
        const char* bs = (const char*)Bs + cur * 8192;
#pragma unroll
        for (int m = 0; m < 4; m++) {
            const int row = wr + m * 16 + rA;
            av[m] = *(const bf16x8*)(as + row * 64 + (kbyte ^ (((row >> 1) & 3) << 4)));
        }
#pragma unroll
        for (int n = 0; n < 4; n++) {
            const int row = wc + n * 16 + rA;
            bv[n] = *(const bf16x8*)(bs + row * 64 + (kbyte ^ (((row >> 1) & 3) << 4)));
        }
#pragma unroll
        for (int m = 0; m < 4; m++)
#pragma unroll
            for (int n = 0; n < 4; n++)
                acc[m][n] = __builtin_amdgcn_mfma_f32_16x16x32_bf16(av[m], bv[n], acc[m][n], 0, 0, 0);

        asm volatile("" ::: "memory");
        __builtin_amdgcn_s_barrier();
        cur = (cur == 2) ? 0 : cur + 1;
        nxt2 = (nxt2 == 2) ? 0 : nxt2 + 1;
    }

    // epilogue. C/D layout: col = lane&15, row = (lane>>4)*4 + r  [m89/m91]
    const int r0 = (lane >> 4) << 2;
    const int cl = lane & 15;
#pragma unroll
    for (int m = 0; m < 4; m++) {
        const long gm = (long)arow0 + wr + m * 16 + r0;
#pragma unroll
        for (int n = 0; n < 4; n++) {
            const long gn = (long)brow0 + wc + n * 16 + cl;
            if (MODE == 0) {
                u16* O = (u16*)Cg + blockIdx.z * sC;
#pragma unroll
                for (int r = 0; r < 4; r++)
                    O[(gm + r) * Nc + gn] = f2bf(acc[m][n][r]);
            } else {
                float* O = (float*)Cg + blockIdx.z * sC;
                const float bb = (MODE == 3) ? bias[gn] : 0.f;
#pragma unroll
                for (int r = 0; r < 4; r++)
                    O[(gm + r) * Nc + gn] = acc[m][n][r] + bb;
            }
        }
    }
}

// ---------------------------------------------------------------------------
// Row softmax over 512 fp32 logits (scale 512^-0.5 folded in), bf16 P written
// IN-PLACE over the fp32 row (P row stride = 1024 u16 = fp32 row stride).
// ---------------------------------------------------------------------------
__global__ __launch_bounds__(256)
void softmax_rows(float* __restrict__ S)
{
    const long r = blockIdx.x;
    float* row = S + r * 512;
    const int t = threadIdx.x;
    const int lane = t & 63, wave = t >> 6;
    const float scale = 0.04419417382415922f;  // 512^-0.5

    float a = row[t] * scale;
    float b = row[t + 256] * scale;

    float m = fmaxf(a, b);
#pragma unroll
    for (int o = 32; o; o >>= 1) m = fmaxf(m, __shfl_xor(m, o, 64));

    __shared__ float red[8];
    if (lane == 0) red[wave] = m;
    __syncthreads();
    m = fmaxf(fmaxf(red[0], red[1]), fmaxf(red[2], red[3]));

    float e0 = __expf(a - m), e1 = __expf(b - m);
    float s = e0 + e1;
#pragma unroll
    for (int o = 32; o; o >>= 1) s += __shfl_xor(s, o, 64);
    if (lane == 0) red[wave + 4] = s;
    __syncthreads();
    s = red[4] + red[5] + red[6] + red[7];
    const float inv = 1.f / s;

    u16* P = (u16*)row;
    P[t]       = f2bf(e0 * inv);
    P[t + 256] = f2bf(e1 * inv);
}

// ---------------------------------------------------------------------------
// Algebra:
//   G[b]  = x[b]^T x[b]           (symmetric)                 bf16 [B,512,512]
//   H[b]  = Wq G[b]               (NT via symmetry: Bt=G)     bf16
//   S[b]  = H[b] Wk^T             (NT, fp32 out)              fp32
//   attn  = softmax(S * 512^-0.5) in-place bf16 (row ld 1024)
//   Rt[b] = (attn[b] Wv)^T  = NT(WvT, attn[b])                bf16
//   Z[b]  = Wp attn[b] Wv   = NT(Wp, Rt[b])                   bf16
//   out   = x Z^T + bp      = NT(x, Z[b]) + bias              fp32
// ---------------------------------------------------------------------------
extern "C" void kernel_launch(void* const* d_in, const int* in_sizes, int n_in,
                              void* d_out, int out_size, void* d_ws, size_t ws_size,
                              hipStream_t stream)
{
    (void)in_sizes; (void)n_in; (void)out_size; (void)ws_size;
    const float* x  = (const float*)d_in[0];
    const float* Wq = (const float*)d_in[1];
    const float* Wk = (const float*)d_in[2];
    const float* Wv = (const float*)d_in[3];
    const float* Wp = (const float*)d_in[4];
    const float* bp = (const float*)d_in[5];
    float* out = (float*)d_out;

    char* ws = (char*)d_ws;
    size_t o = 0;
    auto alloc = [&](size_t bytes) {
        char* p = ws + o;
        o = (o + bytes + 255) & ~(size_t)255;
        return p;
    };
    u16* xb = (u16*)alloc((size_t)BB * TT * NN * 2);    // x bf16 [B,T,N]
    u16* xT = (u16*)alloc((size_t)BB * NN * TT * 2);    // x^T bf16 [B,N,T]
    u16* wb = (u16*)alloc((size_t)4 * NN * NN * 2);     // [Wq|Wk|WvT|Wp]
    u16* G  = (u16*)alloc((size_t)BB * NN * NN * 2);
    u16* H  = (u16*)alloc((size_t)BB * NN * NN * 2);
    float* S = (float*)alloc((size_t)BB * NN * NN * 4); // logits / attn in-place
    u16* Rt = (u16*)alloc((size_t)BB * NN * NN * 2);
    u16* Z  = (u16*)alloc((size_t)BB * NN * NN * 2);

    const u16* wqb  = wb;
    const u16* wkb  = wb + 1 * 262144;
    const u16* wvtb = wb + 2 * 262144;
    const u16* wpb  = wb + 3 * 262144;
    const long NSQ = (long)NN * NN;

    cvt_fused<<<dim3(16, 8, 18), dim3(256), 0, stream>>>(x, Wq, Wk, Wv, Wp, xb, xT, wb);

    const dim3 blk(256);

    // G[b] = xT[b] · xT[b]^T  (K = T = 1024)
    gemm_nt<0><<<dim3(4, 4, 16), blk, 0, stream>>>(xT, xT, G, nullptr,
        NN, TT, TT, TT, (long)NN * TT, (long)NN * TT, NSQ);

    // H[b] = Wq · G[b]
    gemm_nt<0><<<dim3(4, 4, 16), blk, 0, stream>>>(wqb, G, H, nullptr,
        NN, NN, NN, NN, 0, NSQ, NSQ);

    // S[b] = H[b] · Wk^T  (fp32 out)
    gemm_nt<2><<<dim3(4, 4, 16), blk, 0, stream>>>(H, wkb, S, nullptr,
        NN, NN, NN, NN, NSQ, 0, NSQ);

    // attn = softmax(S * scale), bf16 in-place (row stride 1024 u16)
    softmax_rows<<<dim3(BB * NN), blk, 0, stream>>>(S);

    // Rt[b] = (attn[b]·Wv)^T : A = WvT, Bt = attn (ldb = 1024 u16)
    gemm_nt<0><<<dim3(4, 4, 16), blk, 0, stream>>>(wvtb, (const u16*)S, Rt, nullptr,
        NN, NN, NN, 1024, 0, (long)NN * 1024, NSQ);

    // Z[b] = Wp · attn[b] · Wv : A = Wp, Bt = Rt
    gemm_nt<0><<<dim3(4, 4, 16), blk, 0, stream>>>(wpb, Rt, Z, nullptr,
        NN, NN, NN, NN, 0, NSQ, NSQ);

    // out = x · Z^T + bp  (fp32)
    gemm_nt<3><<<dim3(4, 8, 16), blk, 0, stream>>>(xb, Z, out, bp,
        NN, NN, NN, NN, (long)TT * NN, NSQ, (long)TT * NN);
}